// Round 8
// baseline (268.843 us; speedup 1.0000x reference)
//
#include <hip/hip_runtime.h>

#define NQv 20000
#define NSv 8192
#define Cv  112
#define CLSv 20
#define INFF 3.4e38f
#define JINF 0x7fffffff

#define GC 16
#define NCELL 4096
#define CELLH 8.0f
#define INVH 0.125f

#define POOLB 32
#define PT 256
#define PNW (POOLB * PT / 64)       // 128 pool waves -> 64 rows/wave

#define MB (NQv / 32)               // 625 mlp blocks
#define VP 36
// ws layout (floats): [0,3616) pool partials; u16 start[4097] @ float 4096;
// u16 sidx[8192] @ float 8192; total 48 KB.

// ---- prep: pool partials (blocks 0..31) + spatial grid build (block 32)
__global__ __launch_bounds__(PT) void k_prep(const float* __restrict__ cs,
                                             const float* __restrict__ fs7,
                                             const float* __restrict__ wat,
                                             float* __restrict__ ws) {
    __shared__ int  cnt[NCELL];
    __shared__ int  ssum[PT];
    __shared__ float red[PT / 64][Cv + 1];
    int b = blockIdx.x, tid = threadIdx.x;

    if (b == POOLB) {               // grid build: histogram -> prefix -> scatter
        unsigned short* startg = (unsigned short*)(ws + 4096);
        unsigned short* sidxg  = (unsigned short*)(ws + 8192);
        for (int i = tid; i < NCELL; i += PT) cnt[i] = 0;
        __syncthreads();
        for (int k = 0; k < NSv / PT; ++k) {
            int p = k * PT + tid;
            float x = cs[3 * p], y = cs[3 * p + 1], z = cs[3 * p + 2];
            int cx = (int)(x * INVH), cy = (int)(y * INVH), cz = (int)(z * INVH);
            cx = cx > 15 ? 15 : cx; cy = cy > 15 ? 15 : cy; cz = cz > 15 ? 15 : cz;
            atomicAdd(&cnt[(cz * GC + cy) * GC + cx], 1);
        }
        __syncthreads();
        int base = tid * 16, local = 0, c[16];
        #pragma unroll
        for (int i = 0; i < 16; ++i) { c[i] = cnt[base + i]; local += c[i]; }
        ssum[tid] = local;
        __syncthreads();
        for (int off = 1; off < PT; off <<= 1) {   // Hillis-Steele inclusive
            int v = (tid >= off) ? ssum[tid - off] : 0;
            __syncthreads();
            ssum[tid] += v;
            __syncthreads();
        }
        int run = ssum[tid] - local;
        #pragma unroll
        for (int i = 0; i < 16; ++i) {
            startg[base + i] = (unsigned short)run;
            cnt[base + i] = run;                   // cursor
            run += c[i];
        }
        if (tid == 0) startg[NCELL] = (unsigned short)NSv;
        __syncthreads();
        for (int k = 0; k < NSv / PT; ++k) {
            int p = k * PT + tid;
            float x = cs[3 * p], y = cs[3 * p + 1], z = cs[3 * p + 2];
            int cx = (int)(x * INVH), cy = (int)(y * INVH), cz = (int)(z * INVH);
            cx = cx > 15 ? 15 : cx; cy = cy > 15 ? 15 : cy; cz = cz > 15 ? 15 : cz;
            int slot = atomicAdd(&cnt[(cz * GC + cy) * GC + cx], 1);
            sidxg[slot] = (unsigned short)p;
        }
        return;
    }

    // pool partials: ws[b*113 + c] = sum p_i*feat[i][c]; [...112] = sum p_i
    int gtid = b * PT + tid;
    int wid = gtid >> 6, lw = tid >> 6, lane = gtid & 63, l2 = lane * 2;
    float2 wa = make_float2(0.f, 0.f);
    if (lane < 56) wa = *(const float2*)(wat + l2);
    float gx = 0.f, gy = 0.f, z = 0.f;
    for (int g = 0; g < 8; ++g) {               // 8 independent shuffle chains
        float2 f[8]; float part[8];
        #pragma unroll
        for (int u = 0; u < 8; ++u) {
            int i = wid + (g * 8 + u) * PNW;
            f[u] = (lane < 56) ? *(const float2*)(fs7 + i * Cv + l2) : make_float2(0.f, 0.f);
            part[u] = f[u].x * wa.x + f[u].y * wa.y;
        }
        #pragma unroll
        for (int off = 32; off; off >>= 1)
            #pragma unroll
            for (int u = 0; u < 8; ++u) part[u] += __shfl_xor(part[u], off, 64);
        #pragma unroll
        for (int u = 0; u < 8; ++u) {
            float p = __expf(part[u]);          // |logit| small, f32-safe
            gx = fmaf(p, f[u].x, gx); gy = fmaf(p, f[u].y, gy); z += p;
        }
    }
    if (lane < 56) { red[lw][l2] = gx; red[lw][l2 + 1] = gy; }
    if (lane == 0) red[lw][Cv] = z;
    __syncthreads();
    if (tid < Cv + 1)
        ws[b * (Cv + 1) + tid] = red[0][tid] + red[1][tid] + red[2][tid] + red[3][tid];
}

// ---- mlp: grid 3-NN search (8 threads/query) + gate + batched MLP GEMM
__global__ __launch_bounds__(256) void k_mlp(
        const float* __restrict__ cq, const float* __restrict__ cs,
        const float* __restrict__ x7, const float* __restrict__ fs,
        const float* __restrict__ W1, const float* __restrict__ gma,
        const float* __restrict__ bta, const float* __restrict__ W2,
        const float* __restrict__ Wc, const float* __restrict__ bc,
        const float* __restrict__ ws, float* __restrict__ out) {
    __shared__ float big[224 * VP];          // V^T -> h2^T
    __shared__ float tT[Cv * VP];            // h1 post-BN-ReLU
    __shared__ float gate[Cv];
    __shared__ int   qi[32][3];
    __shared__ float qw[32][3];

    int tid = threadIdx.x;
    int q0 = blockIdx.x * 32;

    if (tid < Cv) {                          // gate = sigmoid(pooled mean)
        float st = 0.f, zt = 0.f;
        for (int b = 0; b < POOLB; ++b) {
            st += ws[b * (Cv + 1) + tid];
            zt += ws[b * (Cv + 1) + Cv];
        }
        gate[tid] = 1.0f / (1.0f + __expf(-(st / zt)));
    }

    // ---- exact 3-NN via ring search: 8 threads per query
    {
        const unsigned short* __restrict__ startg = (const unsigned short*)(ws + 4096);
        const unsigned short* __restrict__ sidxg  = (const unsigned short*)(ws + 8192);
        int qg = tid >> 3, sub = tid & 7;
        int q = q0 + qg;
        float qx = cq[3 * q], qy = cq[3 * q + 1], qz = cq[3 * q + 2];
        float q2 = fmaf(qx, qx, fmaf(qy, qy, qz * qz));
        int cx = (int)(qx * INVH), cy = (int)(qy * INVH), cz = (int)(qz * INVH);
        cx = cx > 15 ? 15 : cx; cy = cy > 15 ? 15 : cy; cz = cz > 15 ? 15 : cz;
        float E0 = INFF, E1 = INFF, E2 = INFF;
        int   J0 = JINF, J1 = JINF, J2 = JINF;

        for (int s = 0; s < GC; ++s) {
            int m = 0;
            for (int dz = -s; dz <= s; ++dz) {
                int zc = cz + dz, az = dz < 0 ? -dz : dz;
                for (int dy = -s; dy <= s; ++dy) {
                    int yc = cy + dy, ay = dy < 0 ? -dy : dy;
                    for (int dx = -s; dx <= s; ++dx) {
                        int ax = dx < 0 ? -dx : dx;
                        if (ax != s && ay != s && az != s) continue;   // Chebyshev ring
                        int mm = m++;
                        if ((mm & 7) != sub) continue;                 // 8-way split
                        int xc = cx + dx;
                        if ((unsigned)xc > 15u || (unsigned)yc > 15u || (unsigned)zc > 15u)
                            continue;
                        int cc = (zc * GC + yc) * GC + xc;
                        int a = startg[cc], bnd = startg[cc + 1];
                        for (int k = a; k < bnd; ++k) {
                            int j = sidxg[k];
                            float x = cs[3 * j], y = cs[3 * j + 1], z = cs[3 * j + 2];
                            float s2 = fmaf(x, x, fmaf(y, y, z * z));
                            // identical FMA sequence as prior rounds -> identical e bits
                            float e = fmaf(qx, -2.f * x,
                                      fmaf(qy, -2.f * y, fmaf(qz, -2.f * z, s2)));
                            bool lt2 = (e < E2) || (e == E2 && j < J2);
                            if (lt2) {
                                bool lt1 = (e < E1) || (e == E1 && j < J1);
                                bool lt0 = (e < E0) || (e == E0 && j < J0);
                                E2 = lt1 ? E1 : e;              J2 = lt1 ? J1 : j;
                                E1 = lt0 ? E0 : (lt1 ? e : E1); J1 = lt0 ? J0 : (lt1 ? j : J1);
                                if (lt0) { E0 = e; J0 = j; }
                            }
                        }
                    }
                }
            }
            // merged 3rd-best value across the 8 subs (value-only triple merge)
            float t0 = E0, t1 = E1, t2 = E2;
            #pragma unroll
            for (int off = 1; off <= 4; off <<= 1) {
                float b0 = __shfl_xor(t0, off, 64);
                float b1 = __shfl_xor(t1, off, 64);
                float b2 = __shfl_xor(t2, off, 64);
                float xx = fmaxf(t0, b0), yy = fminf(t1, b1);
                float zz = fmaxf(t1, b1), uu = fminf(t2, b2);
                t0 = fminf(t0, b0);
                t1 = fminf(xx, yy);
                t2 = fminf(fminf(fmaxf(xx, yy), zz), uu);
            }
            // termination: next shell cannot beat 3rd-best (conservative margin)
            float fx = INFF, fy = INFF, fz = INFF;
            if (cx + s + 1 <= 15) fx = (cx + s + 1) * CELLH - qx;
            if (cx - s - 1 >= 0)  fx = fminf(fx, qx - (cx - s) * CELLH);
            if (cy + s + 1 <= 15) fy = (cy + s + 1) * CELLH - qy;
            if (cy - s - 1 >= 0)  fy = fminf(fy, qy - (cy - s) * CELLH);
            if (cz + s + 1 <= 15) fz = (cz + s + 1) * CELLH - qz;
            if (cz - s - 1 >= 0)  fz = fminf(fz, qz - (cz - s) * CELLH);
            float dmin = fminf(fx, fminf(fy, fz));
            if (dmin * dmin > t2 + q2 + 0.01f) break;
        }
        // exact lex pop-merge of the 8 sub-lists (points unique across subs)
        float h0 = E0, h1 = E1, h2 = E2; int g0 = J0, g1 = J1, g2 = J2;
        float EF[3]; int JF[3];
        #pragma unroll
        for (int t = 0; t < 3; ++t) {
            float mv = h0; int mj = g0;
            #pragma unroll
            for (int off = 1; off <= 4; off <<= 1) {
                float ov = __shfl_xor(mv, off, 64);
                int   oj = __shfl_xor(mj, off, 64);
                if (ov < mv || (ov == mv && oj < mj)) { mv = ov; mj = oj; }
            }
            EF[t] = mv; JF[t] = mj;
            bool win = (h0 == mv) && (g0 == mj);
            h0 = win ? h1 : h0; g0 = win ? g1 : g0;
            h1 = win ? h2 : h1; g1 = win ? g2 : g1;
            h2 = win ? INFF : h2; g2 = win ? JINF : g2;
        }
        if (sub == 0) {
            float w1v = __expf(EF[0] - EF[1]);
            float w2v = __expf(EF[0] - EF[2]);
            float iw  = 1.0f / (1.0f + w1v + w2v);
            qw[qg][0] = iw; qw[qg][1] = w1v * iw; qw[qg][2] = w2v * iw;
            qi[qg][0] = (JF[0] < 0 || JF[0] >= NSv) ? 0 : JF[0];
            qi[qg][1] = (JF[1] < 0 || JF[1] >= NSv) ? 0 : JF[1];
            qi[qg][2] = (JF[2] < 0 || JF[2] >= NSv) ? 0 : JF[2];
        }
    }
    __syncthreads();

    // build V^T[224][VP]: rows 0..111 = gated x7, rows 112..223 = matched
    {
        int vq = tid >> 3, e8 = tid & 7;
        int gq = q0 + vq;
        int i0 = qi[vq][0], i1 = qi[vq][1], i2 = qi[vq][2];
        float w0 = qw[vq][0], w1v = qw[vq][1], w2v = qw[vq][2];
        #pragma unroll
        for (int r = 0; r < 14; ++r) {
            int k = e8 + (r << 3);
            float m = w0 * fs[i0 * Cv + k] + w1v * fs[i1 * Cv + k] + w2v * fs[i2 * Cv + k];
            big[k * VP + vq] = x7[gq * Cv + k] * gate[k];
            big[(Cv + k) * VP + vq] = m;
        }
    }
    __syncthreads();

    int tx = tid % 28, ty = tid / 28;        // 4 cols x 4 queries per thread
    int cb = tx * 4, qb = ty * 4;

    if (ty < 8) {                            // h1 = V @ W1 -> BN affine -> ReLU
        float acc[4][4] = {};
        #pragma unroll 4
        for (int k = 0; k < 2 * Cv; ++k) {
            float4 vv = *(const float4*)&big[k * VP + qb];
            float4 ww = *(const float4*)&W1[k * Cv + cb];
            #pragma unroll
            for (int i = 0; i < 4; ++i) {
                float v = (&vv.x)[i];
                acc[i][0] = fmaf(v, ww.x, acc[i][0]);
                acc[i][1] = fmaf(v, ww.y, acc[i][1]);
                acc[i][2] = fmaf(v, ww.z, acc[i][2]);
                acc[i][3] = fmaf(v, ww.w, acc[i][3]);
            }
        }
        #pragma unroll
        for (int j = 0; j < 4; ++j) {
            float g = gma[cb + j], b = bta[cb + j];
            #pragma unroll
            for (int i = 0; i < 4; ++i) {
                float hh = fmaf(acc[i][j], g, b);
                tT[(cb + j) * VP + qb + i] = hh > 0.f ? hh : 0.f;
            }
        }
    }
    __syncthreads();

    if (ty < 8) {                            // h2 = t @ W2
        float acc[4][4] = {};
        #pragma unroll 4
        for (int k = 0; k < Cv; ++k) {
            float4 vv = *(const float4*)&tT[k * VP + qb];
            float4 ww = *(const float4*)&W2[k * Cv + cb];
            #pragma unroll
            for (int i = 0; i < 4; ++i) {
                float v = (&vv.x)[i];
                acc[i][0] = fmaf(v, ww.x, acc[i][0]);
                acc[i][1] = fmaf(v, ww.y, acc[i][1]);
                acc[i][2] = fmaf(v, ww.z, acc[i][2]);
                acc[i][3] = fmaf(v, ww.w, acc[i][3]);
            }
        }
        #pragma unroll
        for (int j = 0; j < 4; ++j)
            #pragma unroll
            for (int i = 0; i < 4; ++i)
                big[(cb + j) * VP + qb + i] = acc[i][j];
    }
    __syncthreads();

    // out = h2 @ Wc + bc
    {
        int qq = tid & 31, cg = tid >> 5;
        int ob = cg * 3;
        if (ob < CLSv) {
            int nc = CLSv - ob; if (nc > 3) nc = 3;
            float a0v = bc[ob];
            float a1v = (nc > 1) ? bc[ob + 1] : 0.f;
            float a2v = (nc > 2) ? bc[ob + 2] : 0.f;
            #pragma unroll 4
            for (int k = 0; k < Cv; ++k) {
                float hh = big[k * VP + qq];
                a0v = fmaf(hh, Wc[k * CLSv + ob], a0v);
                if (nc > 1) a1v = fmaf(hh, Wc[k * CLSv + ob + 1], a1v);
                if (nc > 2) a2v = fmaf(hh, Wc[k * CLSv + ob + 2], a2v);
            }
            float* o = out + (q0 + qq) * CLSv + ob;
            o[0] = a0v;
            if (nc > 1) o[1] = a1v;
            if (nc > 2) o[2] = a2v;
        }
    }
}

extern "C" void kernel_launch(void* const* d_in, const int* in_sizes, int n_in,
                              void* d_out, int out_size, void* d_ws, size_t ws_size,
                              hipStream_t stream) {
    const float* cq  = (const float*)d_in[0];
    const float* cs  = (const float*)d_in[1];
    const float* x7  = (const float*)d_in[2];
    const float* fs7 = (const float*)d_in[3];
    const float* fs  = (const float*)d_in[4];
    const float* wat = (const float*)d_in[5];
    const float* W1  = (const float*)d_in[6];
    const float* gma = (const float*)d_in[7];
    const float* bta = (const float*)d_in[8];
    const float* W2  = (const float*)d_in[9];
    const float* Wc  = (const float*)d_in[10];
    const float* bc  = (const float*)d_in[11];
    float* ws  = (float*)d_ws;
    float* out = (float*)d_out;

    k_prep<<<POOLB + 1, PT, 0, stream>>>(cs, fs7, wat, ws);
    k_mlp<<<MB, 256, 0, stream>>>(cq, cs, x7, fs, W1, gma, bta, W2, Wc, bc, ws, out);
}

// Round 9
// 227.006 us; speedup vs baseline: 1.1843x; 1.1843x over previous
//
#include <hip/hip_runtime.h>

#define NQv 20000
#define NSv 8192
#define Cv  112
#define CLSv 20
#define INFF 3.4e38f
#define JINF 0x7fffffff

#define GC 16
#define NCELL 4096
#define CELLH 8.0f
#define INVH 0.125f

#define POOLB 32
#define PT 256
#define PNW (POOLB * PT / 64)       // 128 pool waves -> 64 rows/wave

#define MB (NQv / 32)               // 625 blocks (search & mlp)
#define VP 36
// ws floats: [0,3616) pool partials; u16 start[4098] @ 3616; pts4 float4[8192] @ 5668
#define WS_START 3616
#define WS_PTS4  5668

// ---- prep: pool partials (blocks 0..31) + cell-sorted point table (block 32)
__global__ __launch_bounds__(PT) void k_prep(const float* __restrict__ cs,
                                             const float* __restrict__ fs7,
                                             const float* __restrict__ wat,
                                             float* __restrict__ ws) {
    int b = blockIdx.x, tid = threadIdx.x;

    if (b == POOLB) {               // grid build: histogram -> prefix -> scatter pts4
        __shared__ int cnt[NCELL];
        __shared__ int ssum[PT];
        unsigned short* startg = (unsigned short*)(ws + WS_START);
        float4* pts4 = (float4*)(ws + WS_PTS4);
        for (int i = tid; i < NCELL; i += PT) cnt[i] = 0;
        __syncthreads();
        for (int k = 0; k < NSv / PT; ++k) {
            int p = k * PT + tid;
            float x = cs[3 * p], y = cs[3 * p + 1], z = cs[3 * p + 2];
            int cx = (int)(x * INVH), cy = (int)(y * INVH), cz = (int)(z * INVH);
            cx = cx > 15 ? 15 : cx; cy = cy > 15 ? 15 : cy; cz = cz > 15 ? 15 : cz;
            atomicAdd(&cnt[(cz * GC + cy) * GC + cx], 1);
        }
        __syncthreads();
        int base = tid * 16, local = 0, c[16];
        #pragma unroll
        for (int i = 0; i < 16; ++i) { c[i] = cnt[base + i]; local += c[i]; }
        ssum[tid] = local;
        __syncthreads();
        for (int off = 1; off < PT; off <<= 1) {   // Hillis-Steele inclusive
            int v = (tid >= off) ? ssum[tid - off] : 0;
            __syncthreads();
            ssum[tid] += v;
            __syncthreads();
        }
        int run = ssum[tid] - local;
        #pragma unroll
        for (int i = 0; i < 16; ++i) {
            startg[base + i] = (unsigned short)run;
            cnt[base + i] = run;                   // cursor
            run += c[i];
        }
        if (tid == 0) startg[NCELL] = (unsigned short)NSv;
        __syncthreads();
        for (int k = 0; k < NSv / PT; ++k) {
            int p = k * PT + tid;
            float x = cs[3 * p], y = cs[3 * p + 1], z = cs[3 * p + 2];
            int cx = (int)(x * INVH), cy = (int)(y * INVH), cz = (int)(z * INVH);
            cx = cx > 15 ? 15 : cx; cy = cy > 15 ? 15 : cy; cz = cz > 15 ? 15 : cz;
            int slot = atomicAdd(&cnt[(cz * GC + cy) * GC + cx], 1);
            pts4[slot] = make_float4(-2.f * x, -2.f * y, -2.f * z, (float)p);
        }
        return;
    }

    // pool partials: ws[b*113 + c] = sum p_i*feat[i][c]; [...112] = sum p_i
    __shared__ float red[PT / 64][Cv + 1];
    int gtid = b * PT + tid;
    int wid = gtid >> 6, lw = tid >> 6, lane = gtid & 63, l2 = lane * 2;
    float2 wa = make_float2(0.f, 0.f);
    if (lane < 56) wa = *(const float2*)(wat + l2);
    float gx = 0.f, gy = 0.f, z = 0.f;
    for (int g = 0; g < 8; ++g) {               // 8 independent shuffle chains
        float2 f[8]; float part[8];
        #pragma unroll
        for (int u = 0; u < 8; ++u) {
            int i = wid + (g * 8 + u) * PNW;
            f[u] = (lane < 56) ? *(const float2*)(fs7 + i * Cv + l2) : make_float2(0.f, 0.f);
            part[u] = f[u].x * wa.x + f[u].y * wa.y;
        }
        #pragma unroll
        for (int off = 32; off; off >>= 1)
            #pragma unroll
            for (int u = 0; u < 8; ++u) part[u] += __shfl_xor(part[u], off, 64);
        #pragma unroll
        for (int u = 0; u < 8; ++u) {
            float p = __expf(part[u]);          // |logit| small, f32-safe
            gx = fmaf(p, f[u].x, gx); gy = fmaf(p, f[u].y, gy); z += p;
        }
    }
    if (lane < 56) { red[lw][l2] = gx; red[lw][l2 + 1] = gy; }
    if (lane == 0) red[lw][Cv] = z;
    __syncthreads();
    if (tid < Cv + 1)
        ws[b * (Cv + 1) + tid] = red[0][tid] + red[1][tid] + red[2][tid] + red[3][tid];
}

// point-stream lex-(e, idx) top-3 insert against canonical FMA chains
__device__ __forceinline__ void scan_run(const float4* __restrict__ pts4,
                                         int a, int b, float qx, float qy, float qz,
                                         float& E0, float& E1, float& E2,
                                         int& J0, int& J1, int& J2) {
    for (int k = a; k < b; ++k) {
        float4 P = pts4[k];
        float x = -0.5f * P.x, y = -0.5f * P.y, z = -0.5f * P.z;   // exact recover
        float s2 = fmaf(x, x, fmaf(y, y, z * z));
        float e = fmaf(qx, P.x, fmaf(qy, P.y, fmaf(qz, P.z, s2)));
        int j = (int)P.w;
        bool lt2 = (e < E2) || (e == E2 && j < J2);
        if (lt2) {
            bool lt1 = (e < E1) || (e == E1 && j < J1);
            bool lt0 = (e < E0) || (e == E0 && j < J0);
            E2 = lt1 ? E1 : e;              J2 = lt1 ? J1 : j;
            E1 = lt0 ? E0 : (lt1 ? e : E1); J1 = lt0 ? J0 : (lt1 ? j : J1);
            if (lt0) { E0 = e; J0 = j; }
        }
    }
}

// ---- search: 32 queries/block, 8 threads/query; sorted-cell runs, ring-exact 3-NN.
// Stash packed orig indices into the query's d_out row (k_mlp overwrites later).
__global__ __launch_bounds__(256) void k_search(const float* __restrict__ cq,
                                                const float* __restrict__ ws,
                                                float* __restrict__ out) {
    const unsigned short* __restrict__ startg = (const unsigned short*)(ws + WS_START);
    const float4* __restrict__ pts4 = (const float4*)(ws + WS_PTS4);
    int tid = threadIdx.x, qg = tid >> 3, sub = tid & 7;
    int q = blockIdx.x * 32 + qg;
    float qx = cq[3 * q], qy = cq[3 * q + 1], qz = cq[3 * q + 2];
    float q2 = fmaf(qx, qx, fmaf(qy, qy, qz * qz));
    int cx = (int)(qx * INVH), cy = (int)(qy * INVH), cz = (int)(qz * INVH);
    cx = cx > 15 ? 15 : cx; cy = cy > 15 ? 15 : cy; cz = cz > 15 ? 15 : cz;
    float E0 = INFF, E1 = INFF, E2 = INFF;
    int   J0 = JINF, J1 = JINF, J2 = JINF;

    // phase 1: 3x3x3 box as <=9 contiguous x-runs, split across 8 subs
    {
        int zlo = cz > 0 ? cz - 1 : 0, zhi = cz < 15 ? cz + 1 : 15;
        int ylo = cy > 0 ? cy - 1 : 0, yhi = cy < 15 ? cy + 1 : 15;
        int xlo = cx > 0 ? cx - 1 : 0, xhi = cx < 15 ? cx + 1 : 15;
        int m = 0;
        for (int zc = zlo; zc <= zhi; ++zc)
            for (int yc = ylo; yc <= yhi; ++yc) {
                if ((m++ & 7) != sub) continue;
                int c0 = (zc * GC + yc) * GC + xlo;
                scan_run(pts4, startg[c0], startg[c0 + (xhi - xlo) + 1],
                         qx, qy, qz, E0, E1, E2, J0, J1, J2);
            }
    }
    // ring expansion until provably exact
    for (int s = 2; s <= 15; ++s) {
        float t0 = E0, t1 = E1, t2 = E2;             // merged 3rd-best value
        #pragma unroll
        for (int off = 1; off <= 4; off <<= 1) {
            float b0 = __shfl_xor(t0, off, 64);
            float b1 = __shfl_xor(t1, off, 64);
            float b2 = __shfl_xor(t2, off, 64);
            float xx = fmaxf(t0, b0), yy = fminf(t1, b1);
            float zz = fmaxf(t1, b1), uu = fminf(t2, b2);
            t0 = fminf(t0, b0);
            t1 = fminf(xx, yy);
            t2 = fminf(fminf(fmaxf(xx, yy), zz), uu);
        }
        int r = s - 1;                               // searched half-width
        int xl = cx - r > 0 ? cx - r : 0, xh = cx + r < 15 ? cx + r : 15;
        int yl = cy - r > 0 ? cy - r : 0, yh = cy + r < 15 ? cy + r : 15;
        int zl = cz - r > 0 ? cz - r : 0, zh = cz + r < 15 ? cz + r : 15;
        float fx = INFF, fy = INFF, fz = INFF;
        if (xl > 0)  fx = qx - xl * CELLH;
        if (xh < 15) fx = fminf(fx, (xh + 1) * CELLH - qx);
        if (yl > 0)  fy = qy - yl * CELLH;
        if (yh < 15) fy = fminf(fy, (yh + 1) * CELLH - qy);
        if (zl > 0)  fz = qz - zl * CELLH;
        if (zh < 15) fz = fminf(fz, (zh + 1) * CELLH - qz);
        float dmin = fminf(fx, fminf(fy, fz));
        if (dmin * dmin > t2 + q2 + 0.5f) break;

        // scan Chebyshev ring s (runs split across subs; m sequence sub-uniform)
        int zlo = cz - s > 0 ? cz - s : 0, zhi = cz + s < 15 ? cz + s : 15;
        int ylo = cy - s > 0 ? cy - s : 0, yhi = cy + s < 15 ? cy + s : 15;
        int xlo = cx - s > 0 ? cx - s : 0, xhi = cx + s < 15 ? cx + s : 15;
        int m = 0;
        for (int zc = zlo; zc <= zhi; ++zc) {
            int az = zc - cz; az = az < 0 ? -az : az;
            for (int yc = ylo; yc <= yhi; ++yc) {
                int ay = yc - cy; ay = ay < 0 ? -ay : ay;
                int rowb = (zc * GC + yc) * GC;
                if (az == s || ay == s) {            // full x-run
                    if ((m++ & 7) == sub)
                        scan_run(pts4, startg[rowb + xlo], startg[rowb + xhi + 1],
                                 qx, qy, qz, E0, E1, E2, J0, J1, J2);
                } else {                             // two single cells at x = cx +- s
                    if (cx - s >= 0 && (m++ & 7) == sub)
                        scan_run(pts4, startg[rowb + cx - s], startg[rowb + cx - s + 1],
                                 qx, qy, qz, E0, E1, E2, J0, J1, J2);
                    if (cx + s <= 15 && (m++ & 7) == sub)
                        scan_run(pts4, startg[rowb + cx + s], startg[rowb + cx + s + 1],
                                 qx, qy, qz, E0, E1, E2, J0, J1, J2);
                }
            }
        }
    }
    // exact lex pop-merge of the 8 sub-lists (points unique across subs)
    float h0 = E0, h1 = E1, h2 = E2; int g0 = J0, g1 = J1, g2 = J2;
    float EF[3]; int JF[3];
    #pragma unroll
    for (int t = 0; t < 3; ++t) {
        float mv = h0; int mj = g0;
        #pragma unroll
        for (int off = 1; off <= 4; off <<= 1) {
            float ov = __shfl_xor(mv, off, 64);
            int   oj = __shfl_xor(mj, off, 64);
            if (ov < mv || (ov == mv && oj < mj)) { mv = ov; mj = oj; }
        }
        EF[t] = mv; JF[t] = mj;
        bool win = (h0 == mv) && (g0 == mj);
        h0 = win ? h1 : h0; g0 = win ? g1 : g0;
        h1 = win ? h2 : h1; g1 = win ? g2 : g1;
        h2 = win ? INFF : h2; g2 = win ? JINF : g2;
    }
    if (sub == 0) {
        int A0 = (JF[0] < 0 || JF[0] >= NSv) ? 0 : JF[0];
        int A1 = (JF[1] < 0 || JF[1] >= NSv) ? 0 : JF[1];
        int A2 = (JF[2] < 0 || JF[2] >= NSv) ? 0 : JF[2];
        ((int*)out)[q * CLSv]     = A0 | (A1 << 16);
        ((int*)out)[q * CLSv + 1] = A2;
    }
}

// ---- mlp: unpack stash, recompute weights (bit-identical e), GEMMs, classifier
__global__ __launch_bounds__(256) void k_mlp(
        const float* __restrict__ cq, const float* __restrict__ cs,
        const float* __restrict__ x7, const float* __restrict__ fs,
        const float* __restrict__ W1, const float* __restrict__ gma,
        const float* __restrict__ bta, const float* __restrict__ W2,
        const float* __restrict__ Wc, const float* __restrict__ bc,
        const float* __restrict__ ws, float* __restrict__ out) {
    __shared__ float big[224 * VP];          // V^T -> h2^T
    __shared__ float tT[Cv * VP];            // h1 post-BN-ReLU
    __shared__ float gate[Cv];
    __shared__ int   qi[32][3];
    __shared__ float qw[32][3];

    int tid = threadIdx.x;
    int q0 = blockIdx.x * 32;

    if (tid < Cv) {                          // gate = sigmoid(pooled mean)
        float st = 0.f, zt = 0.f;
        for (int b = 0; b < POOLB; ++b) {
            st += ws[b * (Cv + 1) + tid];
            zt += ws[b * (Cv + 1) + Cv];
        }
        gate[tid] = 1.0f / (1.0f + __expf(-(st / zt)));
    }
    if (tid < 32) {                          // unpack stash + recompute weights
        int q = q0 + tid;
        int A = ((const int*)out)[q * CLSv];
        int B = ((const int*)out)[q * CLSv + 1];
        int J0 = A & 0xFFFF, J1 = (A >> 16) & 0xFFFF, J2 = B;
        J0 = (J0 < 0 || J0 >= NSv) ? 0 : J0;
        J1 = (J1 < 0 || J1 >= NSv) ? 0 : J1;
        J2 = (J2 < 0 || J2 >= NSv) ? 0 : J2;
        float qx = cq[3 * q], qy = cq[3 * q + 1], qz = cq[3 * q + 2];
        float e[3]; int JJ[3] = {J0, J1, J2};
        #pragma unroll
        for (int r = 0; r < 3; ++r) {
            float x = cs[3 * JJ[r]], y = cs[3 * JJ[r] + 1], z = cs[3 * JJ[r] + 2];
            float s2 = fmaf(x, x, fmaf(y, y, z * z));
            e[r] = fmaf(qx, -2.f * x, fmaf(qy, -2.f * y, fmaf(qz, -2.f * z, s2)));
        }
        float w1v = __expf(e[0] - e[1]);
        float w2v = __expf(e[0] - e[2]);
        float iw  = 1.0f / (1.0f + w1v + w2v);
        qw[tid][0] = iw; qw[tid][1] = w1v * iw; qw[tid][2] = w2v * iw;
        qi[tid][0] = J0; qi[tid][1] = J1; qi[tid][2] = J2;
    }
    __syncthreads();

    // build V^T[224][VP]: rows 0..111 = gated x7, rows 112..223 = matched
    {
        int vq = tid >> 3, e8 = tid & 7;
        int gq = q0 + vq;
        int i0 = qi[vq][0], i1 = qi[vq][1], i2 = qi[vq][2];
        float w0 = qw[vq][0], w1v = qw[vq][1], w2v = qw[vq][2];
        #pragma unroll
        for (int r = 0; r < 14; ++r) {
            int k = e8 + (r << 3);
            float m = w0 * fs[i0 * Cv + k] + w1v * fs[i1 * Cv + k] + w2v * fs[i2 * Cv + k];
            big[k * VP + vq] = x7[gq * Cv + k] * gate[k];
            big[(Cv + k) * VP + vq] = m;
        }
    }
    __syncthreads();

    int tx = tid % 28, ty = tid / 28;        // 4 cols x 4 queries per thread
    int cb = tx * 4, qb = ty * 4;

    if (ty < 8) {                            // h1 = V @ W1 -> BN affine -> ReLU
        float acc[4][4] = {};
        #pragma unroll 4
        for (int k = 0; k < 2 * Cv; ++k) {
            float4 vv = *(const float4*)&big[k * VP + qb];
            float4 ww = *(const float4*)&W1[k * Cv + cb];
            #pragma unroll
            for (int i = 0; i < 4; ++i) {
                float v = (&vv.x)[i];
                acc[i][0] = fmaf(v, ww.x, acc[i][0]);
                acc[i][1] = fmaf(v, ww.y, acc[i][1]);
                acc[i][2] = fmaf(v, ww.z, acc[i][2]);
                acc[i][3] = fmaf(v, ww.w, acc[i][3]);
            }
        }
        #pragma unroll
        for (int j = 0; j < 4; ++j) {
            float g = gma[cb + j], b = bta[cb + j];
            #pragma unroll
            for (int i = 0; i < 4; ++i) {
                float hh = fmaf(acc[i][j], g, b);
                tT[(cb + j) * VP + qb + i] = hh > 0.f ? hh : 0.f;
            }
        }
    }
    __syncthreads();

    if (ty < 8) {                            // h2 = t @ W2
        float acc[4][4] = {};
        #pragma unroll 4
        for (int k = 0; k < Cv; ++k) {
            float4 vv = *(const float4*)&tT[k * VP + qb];
            float4 ww = *(const float4*)&W2[k * Cv + cb];
            #pragma unroll
            for (int i = 0; i < 4; ++i) {
                float v = (&vv.x)[i];
                acc[i][0] = fmaf(v, ww.x, acc[i][0]);
                acc[i][1] = fmaf(v, ww.y, acc[i][1]);
                acc[i][2] = fmaf(v, ww.z, acc[i][2]);
                acc[i][3] = fmaf(v, ww.w, acc[i][3]);
            }
        }
        #pragma unroll
        for (int j = 0; j < 4; ++j)
            #pragma unroll
            for (int i = 0; i < 4; ++i)
                big[(cb + j) * VP + qb + i] = acc[i][j];
    }
    __syncthreads();

    // out = h2 @ Wc + bc  (overwrites stash bytes too)
    {
        int qq = tid & 31, cg = tid >> 5;
        int ob = cg * 3;
        if (ob < CLSv) {
            int nc = CLSv - ob; if (nc > 3) nc = 3;
            float a0v = bc[ob];
            float a1v = (nc > 1) ? bc[ob + 1] : 0.f;
            float a2v = (nc > 2) ? bc[ob + 2] : 0.f;
            #pragma unroll 4
            for (int k = 0; k < Cv; ++k) {
                float hh = big[k * VP + qq];
                a0v = fmaf(hh, Wc[k * CLSv + ob], a0v);
                if (nc > 1) a1v = fmaf(hh, Wc[k * CLSv + ob + 1], a1v);
                if (nc > 2) a2v = fmaf(hh, Wc[k * CLSv + ob + 2], a2v);
            }
            float* o = out + (q0 + qq) * CLSv + ob;
            o[0] = a0v;
            if (nc > 1) o[1] = a1v;
            if (nc > 2) o[2] = a2v;
        }
    }
}

extern "C" void kernel_launch(void* const* d_in, const int* in_sizes, int n_in,
                              void* d_out, int out_size, void* d_ws, size_t ws_size,
                              hipStream_t stream) {
    const float* cq  = (const float*)d_in[0];
    const float* cs  = (const float*)d_in[1];
    const float* x7  = (const float*)d_in[2];
    const float* fs7 = (const float*)d_in[3];
    const float* fs  = (const float*)d_in[4];
    const float* wat = (const float*)d_in[5];
    const float* W1  = (const float*)d_in[6];
    const float* gma = (const float*)d_in[7];
    const float* bta = (const float*)d_in[8];
    const float* W2  = (const float*)d_in[9];
    const float* Wc  = (const float*)d_in[10];
    const float* bc  = (const float*)d_in[11];
    float* ws  = (float*)d_ws;
    float* out = (float*)d_out;

    k_prep<<<POOLB + 1, PT, 0, stream>>>(cs, fs7, wat, ws);
    k_search<<<MB, 256, 0, stream>>>(cq, ws, out);
    k_mlp<<<MB, 256, 0, stream>>>(cq, cs, x7, fs, W1, gma, bta, W2, Wc, bc, ws, out);
}

// Round 10
// 178.471 us; speedup vs baseline: 1.5064x; 1.2719x over previous
//
#include <hip/hip_runtime.h>

#define NQv 20000
#define NSv 8192
#define Cv  112
#define CLSv 20
#define INFF 3.4e38f
#define JINF 0x7fffffff

#define GC 16
#define NCELL 4096
#define CELLH 8.0f
#define INVH 0.125f

#define POOLB 32
#define PT 256
#define PNW (POOLB * PT / 64)       // 128 pool waves -> 64 rows/wave

#define SBLK (NQv / 4)              // 5000 search blocks, wave-per-query
#define MB (NQv / 32)               // 625 mlp blocks
#define VP 36
// ws floats: [0,3616) pool partials; u16 start[4098] @ 3616; pts4 float4[8192] @ 5668
#define WS_START 3616
#define WS_PTS4  5668

// ---- prep: pool partials (blocks 0..31) + cell-sorted point table (block 32)
__global__ __launch_bounds__(PT) void k_prep(const float* __restrict__ cs,
                                             const float* __restrict__ fs7,
                                             const float* __restrict__ wat,
                                             float* __restrict__ ws) {
    int b = blockIdx.x, tid = threadIdx.x;

    if (b == POOLB) {               // grid build: histogram -> prefix -> scatter pts4
        __shared__ int cnt[NCELL];
        __shared__ int ssum[PT];
        unsigned short* startg = (unsigned short*)(ws + WS_START);
        float4* pts4 = (float4*)(ws + WS_PTS4);
        for (int i = tid; i < NCELL; i += PT) cnt[i] = 0;
        __syncthreads();
        for (int k = 0; k < NSv / PT; ++k) {
            int p = k * PT + tid;
            float x = cs[3 * p], y = cs[3 * p + 1], z = cs[3 * p + 2];
            int cx = (int)(x * INVH), cy = (int)(y * INVH), cz = (int)(z * INVH);
            cx = cx > 15 ? 15 : cx; cy = cy > 15 ? 15 : cy; cz = cz > 15 ? 15 : cz;
            atomicAdd(&cnt[(cz * GC + cy) * GC + cx], 1);
        }
        __syncthreads();
        int base = tid * 16, local = 0, c[16];
        #pragma unroll
        for (int i = 0; i < 16; ++i) { c[i] = cnt[base + i]; local += c[i]; }
        ssum[tid] = local;
        __syncthreads();
        for (int off = 1; off < PT; off <<= 1) {   // Hillis-Steele inclusive
            int v = (tid >= off) ? ssum[tid - off] : 0;
            __syncthreads();
            ssum[tid] += v;
            __syncthreads();
        }
        int run = ssum[tid] - local;
        #pragma unroll
        for (int i = 0; i < 16; ++i) {
            startg[base + i] = (unsigned short)run;
            cnt[base + i] = run;                   // cursor
            run += c[i];
        }
        if (tid == 0) startg[NCELL] = (unsigned short)NSv;
        __syncthreads();
        for (int k = 0; k < NSv / PT; ++k) {
            int p = k * PT + tid;
            float x = cs[3 * p], y = cs[3 * p + 1], z = cs[3 * p + 2];
            int cx = (int)(x * INVH), cy = (int)(y * INVH), cz = (int)(z * INVH);
            cx = cx > 15 ? 15 : cx; cy = cy > 15 ? 15 : cy; cz = cz > 15 ? 15 : cz;
            int slot = atomicAdd(&cnt[(cz * GC + cy) * GC + cx], 1);
            pts4[slot] = make_float4(-2.f * x, -2.f * y, -2.f * z, (float)p);
        }
        return;
    }

    // pool partials: ws[b*113 + c] = sum p_i*feat[i][c]; [...112] = sum p_i
    __shared__ float red[PT / 64][Cv + 1];
    int gtid = b * PT + tid;
    int wid = gtid >> 6, lw = tid >> 6, lane = gtid & 63, l2 = lane * 2;
    float2 wa = make_float2(0.f, 0.f);
    if (lane < 56) wa = *(const float2*)(wat + l2);
    float gx = 0.f, gy = 0.f, z = 0.f;
    for (int g = 0; g < 8; ++g) {               // 8 independent shuffle chains
        float2 f[8]; float part[8];
        #pragma unroll
        for (int u = 0; u < 8; ++u) {
            int i = wid + (g * 8 + u) * PNW;
            f[u] = (lane < 56) ? *(const float2*)(fs7 + i * Cv + l2) : make_float2(0.f, 0.f);
            part[u] = f[u].x * wa.x + f[u].y * wa.y;
        }
        #pragma unroll
        for (int off = 32; off; off >>= 1)
            #pragma unroll
            for (int u = 0; u < 8; ++u) part[u] += __shfl_xor(part[u], off, 64);
        #pragma unroll
        for (int u = 0; u < 8; ++u) {
            float p = __expf(part[u]);          // |logit| small, f32-safe
            gx = fmaf(p, f[u].x, gx); gy = fmaf(p, f[u].y, gy); z += p;
        }
    }
    if (lane < 56) { red[lw][l2] = gx; red[lw][l2 + 1] = gy; }
    if (lane == 0) red[lw][Cv] = z;
    __syncthreads();
    if (tid < Cv + 1)
        ws[b * (Cv + 1) + tid] = red[0][tid] + red[1][tid] + red[2][tid] + red[3][tid];
}

// point-stream lex-(e, idx) top-3 insert; canonical FMA chain for e
__device__ __forceinline__ void scan_run(const float4* __restrict__ pts4,
                                         int a, int b, float qx, float qy, float qz,
                                         float& E0, float& E1, float& E2,
                                         int& J0, int& J1, int& J2) {
    for (int k = a; k < b; ++k) {
        float4 P = pts4[k];
        float x = -0.5f * P.x, y = -0.5f * P.y, z = -0.5f * P.z;   // exact recover
        float s2 = fmaf(x, x, fmaf(y, y, z * z));
        float e = fmaf(qx, P.x, fmaf(qy, P.y, fmaf(qz, P.z, s2)));
        int j = (int)P.w;
        bool lt2 = (e < E2) || (e == E2 && j < J2);
        if (lt2) {
            bool lt1 = (e < E1) || (e == E1 && j < J1);
            bool lt0 = (e < E0) || (e == E0 && j < J0);
            E2 = lt1 ? E1 : e;              J2 = lt1 ? J1 : j;
            E1 = lt0 ? E0 : (lt1 ? e : E1); J1 = lt0 ? J0 : (lt1 ? j : J1);
            if (lt0) { E0 = e; J0 = j; }
        }
    }
}

// ---- search: ONE WAVE PER QUERY (20000 waves). Box cells on distinct lanes;
// ring expansion flat across lanes; exact lex pop-merge. Stash into d_out row.
__global__ __launch_bounds__(256) void k_search(const float* __restrict__ cq,
                                                const float* __restrict__ ws,
                                                float* __restrict__ out) {
    const unsigned short* __restrict__ startg = (const unsigned short*)(ws + WS_START);
    const float4* __restrict__ pts4 = (const float4*)(ws + WS_PTS4);
    int tid = threadIdx.x, lane = tid & 63, widx = tid >> 6;
    int q = blockIdx.x * 4 + widx;
    float qx = cq[3 * q], qy = cq[3 * q + 1], qz = cq[3 * q + 2];
    float q2 = fmaf(qx, qx, fmaf(qy, qy, qz * qz));
    int cx = (int)(qx * INVH), cy = (int)(qy * INVH), cz = (int)(qz * INVH);
    cx = cx > 15 ? 15 : cx; cy = cy > 15 ? 15 : cy; cz = cz > 15 ? 15 : cz;
    float E0 = INFF, E1 = INFF, E2 = INFF;
    int   J0 = JINF, J1 = JINF, J2 = JINF;

    // 3x3x3 box: one cell per lane (lane < 27)
    if (lane < 27) {
        int dz = lane / 9 - 1, dy = (lane / 3) % 3 - 1, dx = lane % 3 - 1;
        int xc = cx + dx, yc = cy + dy, zc = cz + dz;
        if ((unsigned)xc < 16u && (unsigned)yc < 16u && (unsigned)zc < 16u) {
            int cc = (zc * GC + yc) * GC + xc;
            scan_run(pts4, startg[cc], startg[cc + 1], qx, qy, qz, E0, E1, E2, J0, J1, J2);
        }
    }

    for (int s = 2; s <= 15; ++s) {
        // merged 3rd-best VALUE across 64 lanes (sorted-triple butterfly)
        float t0 = E0, t1 = E1, t2 = E2;
        #pragma unroll
        for (int off = 1; off < 64; off <<= 1) {
            float b0 = __shfl_xor(t0, off, 64);
            float b1 = __shfl_xor(t1, off, 64);
            float b2 = __shfl_xor(t2, off, 64);
            float xx = fmaxf(t0, b0), yy = fminf(t1, b1);
            float zz = fmaxf(t1, b1), uu = fminf(t2, b2);
            t0 = fminf(t0, b0);
            t1 = fminf(xx, yy);
            t2 = fminf(fminf(fmaxf(xx, yy), zz), uu);
        }
        // termination: searched half-width r = s-1 (wave-uniform)
        int r = s - 1;
        int xl = cx - r > 0 ? cx - r : 0, xh = cx + r < 15 ? cx + r : 15;
        int yl = cy - r > 0 ? cy - r : 0, yh = cy + r < 15 ? cy + r : 15;
        int zl = cz - r > 0 ? cz - r : 0, zh = cz + r < 15 ? cz + r : 15;
        float fx = INFF, fy = INFF, fz = INFF;
        if (xl > 0)  fx = qx - xl * CELLH;
        if (xh < 15) fx = fminf(fx, (xh + 1) * CELLH - qx);
        if (yl > 0)  fy = qy - yl * CELLH;
        if (yh < 15) fy = fminf(fy, (yh + 1) * CELLH - qy);
        if (zl > 0)  fz = qz - zl * CELLH;
        if (zh < 15) fz = fminf(fz, (zh + 1) * CELLH - qz);
        float dmin = fminf(fx, fminf(fy, fz));
        if (dmin * dmin > t2 + q2 + 0.5f) break;

        // Chebyshev ring s: flat enumeration of the (2s+1)^3 box across lanes,
        // interior (Chebyshev < s) and out-of-domain cells skipped
        int side = 2 * s + 1, s2n = side * side, tot = s2n * side;
        for (int idx = lane; idx < tot; idx += 64) {
            int dz = idx / s2n - s;
            int rem = idx - (dz + s) * s2n;
            int dy = rem / side - s;
            int dx = rem - (dy + s) * side - s;
            int ax = dx < 0 ? -dx : dx, ay = dy < 0 ? -dy : dy, az = dz < 0 ? -dz : dz;
            if (ax != s && ay != s && az != s) continue;
            int xc = cx + dx, yc = cy + dy, zc = cz + dz;
            if ((unsigned)xc > 15u || (unsigned)yc > 15u || (unsigned)zc > 15u) continue;
            int cc = (zc * GC + yc) * GC + xc;
            scan_run(pts4, startg[cc], startg[cc + 1], qx, qy, qz, E0, E1, E2, J0, J1, J2);
        }
    }

    // exact lex-(e,idx) pop-merge over 64 lanes (cells disjoint -> no duplicates)
    float h0 = E0, h1 = E1, h2 = E2; int g0 = J0, g1 = J1, g2 = J2;
    float EF[3]; int JF[3];
    #pragma unroll
    for (int t = 0; t < 3; ++t) {
        float mv = h0; int mj = g0;
        #pragma unroll
        for (int off = 1; off < 64; off <<= 1) {
            float ov = __shfl_xor(mv, off, 64);
            int   oj = __shfl_xor(mj, off, 64);
            if (ov < mv || (ov == mv && oj < mj)) { mv = ov; mj = oj; }
        }
        EF[t] = mv; JF[t] = mj;
        bool win = (h0 == mv) && (g0 == mj);
        h0 = win ? h1 : h0; g0 = win ? g1 : g0;
        h1 = win ? h2 : h1; g1 = win ? g2 : g1;
        h2 = win ? INFF : h2; g2 = win ? JINF : g2;
    }
    if (lane == 0) {
        int A0 = (JF[0] < 0 || JF[0] >= NSv) ? 0 : JF[0];
        int A1 = (JF[1] < 0 || JF[1] >= NSv) ? 0 : JF[1];
        int A2 = (JF[2] < 0 || JF[2] >= NSv) ? 0 : JF[2];
        ((int*)out)[q * CLSv]     = A0 | (A1 << 16);
        ((int*)out)[q * CLSv + 1] = A2;
    }
}

// ---- mlp: unpack stash, recompute weights (bit-identical e), GEMMs, classifier
__global__ __launch_bounds__(256) void k_mlp(
        const float* __restrict__ cq, const float* __restrict__ cs,
        const float* __restrict__ x7, const float* __restrict__ fs,
        const float* __restrict__ W1, const float* __restrict__ gma,
        const float* __restrict__ bta, const float* __restrict__ W2,
        const float* __restrict__ Wc, const float* __restrict__ bc,
        const float* __restrict__ ws, float* __restrict__ out) {
    __shared__ float big[224 * VP];          // V^T -> h2^T
    __shared__ float tT[Cv * VP];            // h1 post-BN-ReLU
    __shared__ float gate[Cv];
    __shared__ int   qi[32][3];
    __shared__ float qw[32][3];

    int tid = threadIdx.x;
    int q0 = blockIdx.x * 32;

    if (tid < Cv) {                          // gate = sigmoid(pooled mean)
        float st = 0.f, zt = 0.f;
        for (int b = 0; b < POOLB; ++b) {
            st += ws[b * (Cv + 1) + tid];
            zt += ws[b * (Cv + 1) + Cv];
        }
        gate[tid] = 1.0f / (1.0f + __expf(-(st / zt)));
    }
    if (tid < 32) {                          // unpack stash + recompute weights
        int q = q0 + tid;
        int A = ((const int*)out)[q * CLSv];
        int B = ((const int*)out)[q * CLSv + 1];
        int J0 = A & 0xFFFF, J1 = (A >> 16) & 0xFFFF, J2 = B;
        J0 = (J0 < 0 || J0 >= NSv) ? 0 : J0;
        J1 = (J1 < 0 || J1 >= NSv) ? 0 : J1;
        J2 = (J2 < 0 || J2 >= NSv) ? 0 : J2;
        float qx = cq[3 * q], qy = cq[3 * q + 1], qz = cq[3 * q + 2];
        float e[3]; int JJ[3] = {J0, J1, J2};
        #pragma unroll
        for (int r = 0; r < 3; ++r) {
            float x = cs[3 * JJ[r]], y = cs[3 * JJ[r] + 1], z = cs[3 * JJ[r] + 2];
            float s2 = fmaf(x, x, fmaf(y, y, z * z));
            e[r] = fmaf(qx, -2.f * x, fmaf(qy, -2.f * y, fmaf(qz, -2.f * z, s2)));
        }
        float w1v = __expf(e[0] - e[1]);
        float w2v = __expf(e[0] - e[2]);
        float iw  = 1.0f / (1.0f + w1v + w2v);
        qw[tid][0] = iw; qw[tid][1] = w1v * iw; qw[tid][2] = w2v * iw;
        qi[tid][0] = J0; qi[tid][1] = J1; qi[tid][2] = J2;
    }
    __syncthreads();

    // build V^T[224][VP]: rows 0..111 = gated x7, rows 112..223 = matched
    {
        int vq = tid >> 3, e8 = tid & 7;
        int gq = q0 + vq;
        int i0 = qi[vq][0], i1 = qi[vq][1], i2 = qi[vq][2];
        float w0 = qw[vq][0], w1v = qw[vq][1], w2v = qw[vq][2];
        #pragma unroll
        for (int r = 0; r < 14; ++r) {
            int k = e8 + (r << 3);
            float m = w0 * fs[i0 * Cv + k] + w1v * fs[i1 * Cv + k] + w2v * fs[i2 * Cv + k];
            big[k * VP + vq] = x7[gq * Cv + k] * gate[k];
            big[(Cv + k) * VP + vq] = m;
        }
    }
    __syncthreads();

    int tx = tid % 28, ty = tid / 28;        // 4 cols x 4 queries per thread
    int cb = tx * 4, qb = ty * 4;

    if (ty < 8) {                            // h1 = V @ W1 -> BN affine -> ReLU
        float acc[4][4] = {};
        #pragma unroll 4
        for (int k = 0; k < 2 * Cv; ++k) {
            float4 vv = *(const float4*)&big[k * VP + qb];
            float4 ww = *(const float4*)&W1[k * Cv + cb];
            #pragma unroll
            for (int i = 0; i < 4; ++i) {
                float v = (&vv.x)[i];
                acc[i][0] = fmaf(v, ww.x, acc[i][0]);
                acc[i][1] = fmaf(v, ww.y, acc[i][1]);
                acc[i][2] = fmaf(v, ww.z, acc[i][2]);
                acc[i][3] = fmaf(v, ww.w, acc[i][3]);
            }
        }
        #pragma unroll
        for (int j = 0; j < 4; ++j) {
            float g = gma[cb + j], b = bta[cb + j];
            #pragma unroll
            for (int i = 0; i < 4; ++i) {
                float hh = fmaf(acc[i][j], g, b);
                tT[(cb + j) * VP + qb + i] = hh > 0.f ? hh : 0.f;
            }
        }
    }
    __syncthreads();

    if (ty < 8) {                            // h2 = t @ W2
        float acc[4][4] = {};
        #pragma unroll 4
        for (int k = 0; k < Cv; ++k) {
            float4 vv = *(const float4*)&tT[k * VP + qb];
            float4 ww = *(const float4*)&W2[k * Cv + cb];
            #pragma unroll
            for (int i = 0; i < 4; ++i) {
                float v = (&vv.x)[i];
                acc[i][0] = fmaf(v, ww.x, acc[i][0]);
                acc[i][1] = fmaf(v, ww.y, acc[i][1]);
                acc[i][2] = fmaf(v, ww.z, acc[i][2]);
                acc[i][3] = fmaf(v, ww.w, acc[i][3]);
            }
        }
        #pragma unroll
        for (int j = 0; j < 4; ++j)
            #pragma unroll
            for (int i = 0; i < 4; ++i)
                big[(cb + j) * VP + qb + i] = acc[i][j];
    }
    __syncthreads();

    // out = h2 @ Wc + bc  (overwrites stash bytes too)
    {
        int qq = tid & 31, cg = tid >> 5;
        int ob = cg * 3;
        if (ob < CLSv) {
            int nc = CLSv - ob; if (nc > 3) nc = 3;
            float a0v = bc[ob];
            float a1v = (nc > 1) ? bc[ob + 1] : 0.f;
            float a2v = (nc > 2) ? bc[ob + 2] : 0.f;
            #pragma unroll 4
            for (int k = 0; k < Cv; ++k) {
                float hh = big[k * VP + qq];
                a0v = fmaf(hh, Wc[k * CLSv + ob], a0v);
                if (nc > 1) a1v = fmaf(hh, Wc[k * CLSv + ob + 1], a1v);
                if (nc > 2) a2v = fmaf(hh, Wc[k * CLSv + ob + 2], a2v);
            }
            float* o = out + (q0 + qq) * CLSv + ob;
            o[0] = a0v;
            if (nc > 1) o[1] = a1v;
            if (nc > 2) o[2] = a2v;
        }
    }
}

extern "C" void kernel_launch(void* const* d_in, const int* in_sizes, int n_in,
                              void* d_out, int out_size, void* d_ws, size_t ws_size,
                              hipStream_t stream) {
    const float* cq  = (const float*)d_in[0];
    const float* cs  = (const float*)d_in[1];
    const float* x7  = (const float*)d_in[2];
    const float* fs7 = (const float*)d_in[3];
    const float* fs  = (const float*)d_in[4];
    const float* wat = (const float*)d_in[5];
    const float* W1  = (const float*)d_in[6];
    const float* gma = (const float*)d_in[7];
    const float* bta = (const float*)d_in[8];
    const float* W2  = (const float*)d_in[9];
    const float* Wc  = (const float*)d_in[10];
    const float* bc  = (const float*)d_in[11];
    float* ws  = (float*)d_ws;
    float* out = (float*)d_out;

    k_prep<<<POOLB + 1, PT, 0, stream>>>(cs, fs7, wat, ws);
    k_search<<<SBLK, 256, 0, stream>>>(cq, ws, out);
    k_mlp<<<MB, 256, 0, stream>>>(cq, cs, x7, fs, W1, gma, bta, W2, Wc, bc, ws, out);
}